// Round 7
// baseline (135.680 us; speedup 1.0000x reference)
//
#include <hip/hip_runtime.h>

// LogSignature depth-4, C=16, B=64, L=256, fp32.
// out per batch: [lvl1(16) | lvl2(256) | lvl3(4096) | lvl4(65536)] = 69904
//
// v8: back to the proven 3-kernel split (cooperative fusion refuted: grid.sync
// cost >> k_log; and ~52us of dur_us is fixed harness overhead — k_scan is the
// only lever). k_scan rework attacks the DS pipe (the R3-R6 binding constraint:
// 16 uniform ds_read_b128 row-broadcasts/4-steps = 45% stall at VALUBusy 55%):
//   - rows come from global dx1 [j][t][16] (wave-uniform broadcast loads on the
//     ~idle VMEM pipe; dx1 is 1 MB, L2-resident) with a 1-step-ahead register
//     ping-pong (named buffers, fully unrolled, no runtime indexing).
//   - per-lane streams stay in LDS Lc [i][260] (4 conflict-free b128/4-steps).
//   - inner 32 FMAs as 16 v_pk_fma_f32; step 255 zero-padded (uniform loop,
//     no tail; prefetch overrun at t=256 lands in a 16-float ws pad).
//   - DS ops/4-steps: 20 -> 4. VALU floor ~25us.
// k_dx: dx1 only (time-major diffs, row 255 zeroed). k_log: v4 verbatim.
//
// ws (floats): dx1 [64][256][16] | pad 16 | sigA [64][4368] | sigB [64][4368]

#define NC 16
#define NL 256
#define NB 64
#define OUTB 69904
#define SIG123 4368
#define OFF_L2 16
#define OFF_L3 272
#define OFF_L4 4368
#define LCS 260  // padded component-major stride (floats): 260 % 32 = 4 -> conflict-free

#define DX1_OFF 0
#define SIGA_OFF (NB * NL * NC + 16)
#define SIGB_OFF (SIGA_OFF + NB * SIG123)

typedef float v2f __attribute__((ext_vector_type(2)));

// One block per batch j: stage path[j] (16 KB) in LDS, write time-major diffs
// dx1[j][t][i], row 255 zeroed.
__global__ __launch_bounds__(256) void k_dx(const float* __restrict__ path,
                                            float* __restrict__ dx1) {
    const int j = blockIdx.x;
    const int tid = threadIdx.x;
    __shared__ float L[NL * NC];  // 16 KB, [t][i]

    const float* pj = path + (size_t)j * NL * NC;
#pragma unroll
    for (int k = 0; k < 4; ++k) {
        const int f = tid + k * 256;  // float4 index
        *(float4*)&L[f * 4] = *(const float4*)&pj[f * 4];
    }
    __syncthreads();

    float* d1 = dx1 + (size_t)j * NL * NC;
#pragma unroll
    for (int k = 0; k < 16; ++k) {
        const int f = tid + k * 256;
        d1[f] = (f < (NL - 1) * NC) ? (L[f + NC] - L[f]) : 0.f;
    }
}

// Chunk-local signature scan: block (j,a), 256 threads = {h(1b)|b(4b)|c0(3b)},
// c-pair per thread, 2-way in-block time split (Chen), 128 steps each (incl.
// the zero step 255 for h=1).
__global__ __launch_bounds__(256, 4) void k_scan(const float* __restrict__ dx1,
                                                 float* __restrict__ out,
                                                 float* __restrict__ sigA,
                                                 float* __restrict__ sigB) {
    const int bid = blockIdx.x;
    const int j = bid >> 4;
    const int a = bid & 15;
    const int tid = threadIdx.x;
    const int h = tid >> 7;          // time chunk: 0 -> [0,128), 1 -> [128,256)
    const int b = (tid >> 3) & 15;
    const int c0 = tid & 7;          // owns c0 and c0+8

    __shared__ float Lc[NC * LCS];   // component-major diffs [i][t], padded
    __shared__ float ls[4096];       // epilogue merge buffer (16 KB)

    const float* dx1j = dx1 + (size_t)j * NL * NC;

    // build Lc from dx1 (coalesced global read, scattered conflict-lite writes)
#pragma unroll
    for (int k = 0; k < 4; ++k) {
        const int f = tid + k * 256;  // float4 index 0..1023
        const float4 v = *(const float4*)(dx1j + f * 4);
        const int t = f >> 2;         // time index 0..255
        const int i0 = 4 * (f & 3);   // component base
        Lc[(i0 + 0) * LCS + t] = v.x;
        Lc[(i0 + 1) * LCS + t] = v.y;
        Lc[(i0 + 2) * LCS + t] = v.z;
        Lc[(i0 + 3) * LCS + t] = v.w;
    }
    __syncthreads();

    v2f s4a[8], s4b[8];
#pragma unroll
    for (int d = 0; d < 8; ++d) { s4a[d] = (v2f){0.f, 0.f}; s4b[d] = (v2f){0.f, 0.f}; }
    float s3_0 = 0.f, s3_1 = 0.f, s2ab = 0.f, s1a = 0.f;

    auto body = [&](const float4& q0, const float4& q1, const float4& q2,
                    const float4& q3, float dxa, float dxb, float dxc0, float dxc1) {
        const float P = dxb * s1a;
        const float Q = dxb * dxa;
        const float pre4 = fmaf(1.f / 6.f, P, fmaf(1.f / 24.f, Q, 0.5f * s2ab));
        const float U = fmaf(0.5f, P, fmaf(1.f / 6.f, Q, s2ab));
        const float T0 = fmaf(dxc0, pre4, s3_0);
        const float T1 = fmaf(dxc1, pre4, s3_1);
        const v2f dv2[8] = {{q0.x, q0.y}, {q0.z, q0.w}, {q1.x, q1.y}, {q1.z, q1.w},
                            {q2.x, q2.y}, {q2.z, q2.w}, {q3.x, q3.y}, {q3.z, q3.w}};
        const v2f T0v = {T0, T0};
        const v2f T1v = {T1, T1};
#pragma unroll
        for (int d = 0; d < 8; ++d) {
            s4a[d] = __builtin_elementwise_fma(dv2[d], T0v, s4a[d]);  // v_pk_fma_f32
            s4b[d] = __builtin_elementwise_fma(dv2[d], T1v, s4b[d]);
        }
        s3_0 = fmaf(dxc0, U, s3_0);
        s3_1 = fmaf(dxc1, U, s3_1);
        s2ab = fmaf(dxb, fmaf(0.5f, dxa, s1a), s2ab);
        s1a += dxa;
    };

#define LOADROW(R0, R1, R2, R3, tt)                      \
    R0 = *(const float4*)(dx1j + (tt) * NC);             \
    R1 = *(const float4*)(dx1j + (tt) * NC + 4);         \
    R2 = *(const float4*)(dx1j + (tt) * NC + 8);         \
    R3 = *(const float4*)(dx1j + (tt) * NC + 12);

    int t = h * 128;
    float4 A0, A1, A2, A3, B0, B1, B2, B3;
    LOADROW(A0, A1, A2, A3, t)   // prologue: row t0
    for (int it = 0; it < 32; ++it, t += 4) {
        const float4 va = *(const float4*)(Lc + a * LCS + t);         // broadcast
        const float4 vb = *(const float4*)(Lc + b * LCS + t);         // conflict-free
        const float4 vc0 = *(const float4*)(Lc + c0 * LCS + t);
        const float4 vc1 = *(const float4*)(Lc + (c0 + 8) * LCS + t);
        // register ping-pong: issue next row's broadcast load, compute current
        LOADROW(B0, B1, B2, B3, t + 1)
        body(A0, A1, A2, A3, va.x, vb.x, vc0.x, vc1.x);
        LOADROW(A0, A1, A2, A3, t + 2)
        body(B0, B1, B2, B3, va.y, vb.y, vc0.y, vc1.y);
        LOADROW(B0, B1, B2, B3, t + 3)
        body(A0, A1, A2, A3, va.z, vb.z, vc0.z, vc1.z);
        LOADROW(A0, A1, A2, A3, t + 4)   // t=256 overrun lands in ws pad
        body(B0, B1, B2, B3, va.w, vb.w, vc0.w, vc1.w);
    }
#undef LOADROW

    // epilogue: merge A4 + B4 in LDS (both chunks live in this block),
    // write ONE 16 KB slice. Cross terms are k_log's job.
    __syncthreads();
    const int base = b * 256 + c0 * 16;
    if (h == 0) {
#pragma unroll
        for (int d = 0; d < 4; ++d) {
            *(float4*)&ls[base + d * 4] = make_float4(
                s4a[2 * d].x, s4a[2 * d].y, s4a[2 * d + 1].x, s4a[2 * d + 1].y);
            *(float4*)&ls[base + 128 + d * 4] = make_float4(
                s4b[2 * d].x, s4b[2 * d].y, s4b[2 * d + 1].x, s4b[2 * d + 1].y);
        }
    }
    __syncthreads();
    if (h == 1) {
#pragma unroll
        for (int d = 0; d < 4; ++d) {
            float4 v0 = *(const float4*)&ls[base + d * 4];
            v0.x += s4a[2 * d].x; v0.y += s4a[2 * d].y;
            v0.z += s4a[2 * d + 1].x; v0.w += s4a[2 * d + 1].y;
            *(float4*)&ls[base + d * 4] = v0;
            float4 v1 = *(const float4*)&ls[base + 128 + d * 4];
            v1.x += s4b[2 * d].x; v1.y += s4b[2 * d].y;
            v1.z += s4b[2 * d + 1].x; v1.w += s4b[2 * d + 1].y;
            *(float4*)&ls[base + 128 + d * 4] = v1;
        }
    }
    __syncthreads();
    {
        float* o4 = out + (size_t)j * OUTB + OFF_L4 + a * 4096;
#pragma unroll
        for (int k = 0; k < 4; ++k) {
            const int f = tid + k * 256;  // float4 index 0..1023
            *(float4*)(o4 + f * 4) = *(const float4*)&ls[f * 4];
        }
    }

    // levels 1-3 of this thread's chunk
    float* sg = (h ? sigB : sigA) + (size_t)j * SIG123;
    sg[OFF_L3 + (a * 16 + b) * 16 + c0] = s3_0;
    sg[OFF_L3 + (a * 16 + b) * 16 + c0 + 8] = s3_1;
    if (c0 == 0) sg[OFF_L2 + a * 16 + b] = s2ab;
    if ((tid & 127) == 0) sg[a] = s1a;
}

// Chen cross-terms (S4 = [A4+B4] + A1(x)B3 + A2(x)B2 + A3(x)B1) + log
// correction. Block (j,a). Merged S1/S2/S3 in LDS (~20 KB); B3 from global
// (L2-resident).
__global__ __launch_bounds__(256) void k_log(const float* __restrict__ sigA,
                                             const float* __restrict__ sigB,
                                             float* __restrict__ out) {
    const int bid = blockIdx.x;
    const int j = bid >> 4;
    const int a = bid & 15;
    const int tid = threadIdx.x;
    const int q = tid >> 4;
    const int r = tid & 15;

    const float* A = sigA + (size_t)j * SIG123;
    const float* Bp = sigB + (size_t)j * SIG123;

    __shared__ float S1m[16], B1s[16], A2s[16];
    __shared__ float S2m[256], B2s[256], A3s[256];
    __shared__ float S3m[4096];

    const float b1r = Bp[r];             // B1[r]
    const float b2t = Bp[OFF_L2 + tid];  // B2[q,r]

    if (tid < 16) {
        const float bb = Bp[tid];
        B1s[tid] = bb;
        S1m[tid] = A[tid] + bb;               // S1 = A1 + B1
        A2s[tid] = A[OFF_L2 + a * 16 + tid];  // A2[a,:]
    }
    B2s[tid] = b2t;
    S2m[tid] = A[OFF_L2 + tid] + b2t + A[q] * b1r;  // S2 = A2 + B2 + A1(x)B1
    A3s[tid] = A[OFF_L3 + a * 256 + tid];           // A3[a,:,:]
#pragma unroll
    for (int k = 0; k < 16; ++k) {  // S3[p,q,r] = A3 + B3 + A1[p]B2[qr] + A2[pq]B1[r]
        const int m = k * 256 + tid;
        S3m[m] = A[OFF_L3 + m] + Bp[OFF_L3 + m] + A[k] * b2t + A[OFF_L2 + k * 16 + q] * b1r;
    }
    __syncthreads();

    const float s1a = S1m[a];
    const float A1a = A[a];
    float* outj = out + (size_t)j * OUTB;
    float* o4 = outj + OFF_L4 + a * 4096;
    const float Ac = -0.5f * s1a;

#pragma unroll
    for (int k = 0; k < 4; ++k) {
        const int f = tid + k * 256;
        const int m0 = f * 4;  // element offset: bb*256 + cc*16 + d0
        const int bb = m0 >> 8;
        const int cc = (m0 >> 4) & 15;
        const float s1b = S1m[bb], s1c = S1m[cc];
        const float s2ab = S2m[a * 16 + bb];
        const float s2bc = S2m[bb * 16 + cc];
        const float s3abc = S3m[a * 256 + (m0 >> 4)];  // merged S3[a,b,c]
        const float a3x = A3s[m0 >> 4];                // A3[a,b,c]
        const float a2x = A2s[bb];                     // A2[a,b]

        const float4 a4 = *(const float4*)(o4 + m0);            // A4+B4
        const float4 b3v = *(const float4*)(Bp + OFF_L3 + m0);  // B3[b,c,d..] (L2)
        const float4 b2v = *(const float4*)(&B2s[m0 & 255]);
        const float4 b1v = *(const float4*)(&B1s[m0 & 15]);
        const float4 v3 = *(const float4*)(&S3m[m0]);
        const float4 v2 = *(const float4*)(&S2m[m0 & 255]);
        const float4 v1 = *(const float4*)(&S1m[m0 & 15]);

        const float Bv = fmaf((1.f / 3.f) * s1a, s1b, -0.5f * s2ab);
        const float Cv = -0.5f * s3abc + (1.f / 3.f) * fmaf(s1a, s2bc, s2ab * s1c)
                         - 0.25f * s1a * s1b * s1c;
        float4 rv;
        // merged S4 = (A4+B4) + A1[a]B3[bcd] + A2[ab]B2[cd] + A3[abc]B1[d]
        rv.x = a4.x + fmaf(A1a, b3v.x, fmaf(a2x, b2v.x, a3x * b1v.x));
        rv.y = a4.y + fmaf(A1a, b3v.y, fmaf(a2x, b2v.y, a3x * b1v.y));
        rv.z = a4.z + fmaf(A1a, b3v.z, fmaf(a2x, b2v.z, a3x * b1v.z));
        rv.w = a4.w + fmaf(A1a, b3v.w, fmaf(a2x, b2v.w, a3x * b1v.w));
        // log correction
        rv.x = fmaf(Ac, v3.x, rv.x) + fmaf(Bv, v2.x, Cv * v1.x);
        rv.y = fmaf(Ac, v3.y, rv.y) + fmaf(Bv, v2.y, Cv * v1.y);
        rv.z = fmaf(Ac, v3.z, rv.z) + fmaf(Bv, v2.z, Cv * v1.z);
        rv.w = fmaf(Ac, v3.w, rv.w) + fmaf(Bv, v2.w, Cv * v1.w);
        *(float4*)(o4 + m0) = rv;
    }

    // level 3 (coalesced)
    {
        const float s1b = S1m[q], s1c = S1m[r];
        const float s2ab = S2m[a * 16 + q];
        const float s2bc = S2m[q * 16 + r];
        const float s3abc = S3m[a * 256 + tid];
        const float r3 = s3abc - 0.5f * fmaf(s1a, s2bc, s2ab * s1c)
                         + (1.f / 3.f) * s1a * s1b * s1c;
        outj[OFF_L3 + a * 256 + tid] = r3;
    }
    // level 2
    if (tid < 16) outj[OFF_L2 + a * 16 + tid] = fmaf(-0.5f * s1a, S1m[tid], S2m[a * 16 + tid]);
    // level 1
    if (tid == 0) outj[a] = s1a;
}

extern "C" void kernel_launch(void* const* d_in, const int* in_sizes, int n_in,
                              void* d_out, int out_size, void* d_ws, size_t ws_size,
                              hipStream_t stream) {
    const float* path = (const float*)d_in[0];
    float* out = (float*)d_out;
    float* ws = (float*)d_ws;
    float* dx1 = ws + DX1_OFF;
    float* sigA = ws + SIGA_OFF;
    float* sigB = ws + SIGB_OFF;

    k_dx<<<NB, 256, 0, stream>>>(path, dx1);
    k_scan<<<NB * 16, 256, 0, stream>>>(dx1, out, sigA, sigB);
    k_log<<<NB * 16, 256, 0, stream>>>(sigA, sigB, out);
}